// Round 11
// baseline (640.494 us; speedup 1.0000x reference)
//
#include <hip/hip_runtime.h>
#include <hip/hip_bf16.h>

#define N_NODES 10000
#define HID 256
#define IN_F 128
#define E_CON 320000
#define E_DST 100000
#define E_TRN 50000

typedef __attribute__((ext_vector_type(8))) short short8v;
typedef __attribute__((ext_vector_type(4))) float f32x4;
typedef unsigned int uint4v __attribute__((ext_vector_type(4)));

__device__ __forceinline__ float b2f(unsigned int u) {
    return __uint_as_float(u << 16);
}
__device__ __forceinline__ unsigned short f2b(float f) {
    unsigned int u = __float_as_uint(f);
    unsigned int r = (u + 0x7fffu + ((u >> 16) & 1u)) >> 16;
    return (unsigned short)r;
}

// Real XCD id (0..7). HW_REG_XCC_ID = 20, 4 bits at offset 0 [measured m09].
// A garbage value only costs locality, never correctness (buckets are drained
// by every wave's 8-step loop regardless).
__device__ __forceinline__ int get_xcc_id() {
    return (int)(__builtin_amdgcn_s_getreg((3 << 11) | (0 << 6) | 20) & 7u);
}

// ---------------- CSR build (fused, 3 graphs) ----------------

struct GraphDesc {
    const int* src;
    const int* dst;
    int nE;
    int* cur;
    int* off;
    int* srt;
};
struct CsrArgs { GraphDesc g[3]; };

__global__ void hist3(CsrArgs a) {
    const GraphDesc& gg = a.g[blockIdx.y];
    int i = blockIdx.x * blockDim.x + threadIdx.x;
    if (i < gg.nE) atomicAdd(&gg.cur[gg.dst[i]], 1);
}

__global__ void fill3(CsrArgs a) {
    const GraphDesc& gg = a.g[blockIdx.y];
    int i = blockIdx.x * blockDim.x + threadIdx.x;
    if (i < gg.nE) {
        int p = atomicAdd(&gg.cur[gg.dst[i]], 1);
        gg.srt[p] = gg.src[i];
    }
}

// One block per graph, 1024 threads, shfl-based exclusive scan over N_NODES.
__global__ __launch_bounds__(1024) void scan3(CsrArgs a) {
    const GraphDesc& gg = a.g[blockIdx.x];
    int* cur = gg.cur;
    int* off = gg.off;
    const int n = N_NODES;
    __shared__ int wsum[16];
    __shared__ int wtot;
    __shared__ int carry_sh;
    int tid = threadIdx.x;
    int lane = tid & 63;
    int w = tid >> 6;
    if (tid == 0) carry_sh = 0;
    __syncthreads();
    for (int base = 0; base < n; base += 1024) {
        int i = base + tid;
        int v = (i < n) ? cur[i] : 0;
        int s = v;
        #pragma unroll
        for (int d = 1; d < 64; d <<= 1) {
            int t = __shfl_up(s, d, 64);
            if (lane >= d) s += t;
        }
        if (lane == 63) wsum[w] = s;
        __syncthreads();
        if (w == 0 && lane < 16) {
            int t = wsum[lane];
            int ss = t;
            #pragma unroll
            for (int d = 1; d < 16; d <<= 1) {
                int u = __shfl_up(ss, d, 64);
                if (lane >= d) ss += u;
            }
            wsum[lane] = ss - t;
            if (lane == 15) wtot = ss;
        }
        __syncthreads();
        int carry = carry_sh;
        int excl = s - v + wsum[w] + carry;
        if (i < n) { off[i] = excl; cur[i] = excl; }
        __syncthreads();
        if (tid == 0) carry_sh += wtot;
        __syncthreads();
    }
    if (threadIdx.x == 0) off[n] = carry_sh;
}

// ---------------- fused prep: weight pack + x0 cvt + cursor/queue zero ----------------

struct PackArgs {
    const float* W[12];
    unsigned short* O[12];
    int K[12];
};

#define N_QUEUE (7 * 256 * 2)   /* 7 passes x 8 buckets x 32-int stride, ctr + done */
#define PREP_PACK_BLKS 384      /* 12 matrices x 32 blocks */
#define PREP_CVT_BLKS  1250     /* 320000 float4 / 256 */
#define PREP_ZERO_BLKS 132      /* 30000 + 3584 ints / 256 */

__global__ void prep_kernel(PackArgs pa, const float* __restrict__ x0,
                            unsigned short* __restrict__ x0b, int* __restrict__ cur_all) {
    int bid = blockIdx.x;
    int tid = threadIdx.x;
    if (bid < PREP_PACK_BLKS) {
        int m = bid >> 5;
        int K = pa.K[m];
        int granules = (K / 32) * 1024;
        int p = (bid & 31) * 256 + tid;
        if (p >= granules) return;
        int kb = p >> 10;
        int r  = p & 1023;
        int c  = r >> 2;
        int gp = r & 3;
        int g  = gp ^ ((c >> 1) & 3);
        const float* W = pa.W[m];
        unsigned short* O = pa.O[m] + (size_t)p * 8;
        int krow = kb * 32 + g * 8;
        ushort4 lo, hi;
        lo.x = f2b(W[(size_t)(krow + 0) * HID + c]);
        lo.y = f2b(W[(size_t)(krow + 1) * HID + c]);
        lo.z = f2b(W[(size_t)(krow + 2) * HID + c]);
        lo.w = f2b(W[(size_t)(krow + 3) * HID + c]);
        hi.x = f2b(W[(size_t)(krow + 4) * HID + c]);
        hi.y = f2b(W[(size_t)(krow + 5) * HID + c]);
        hi.z = f2b(W[(size_t)(krow + 6) * HID + c]);
        hi.w = f2b(W[(size_t)(krow + 7) * HID + c]);
        *(ushort4*)&O[0] = lo;
        *(ushort4*)&O[4] = hi;
    } else if (bid < PREP_PACK_BLKS + PREP_CVT_BLKS) {
        int i = (bid - PREP_PACK_BLKS) * 256 + tid;   // < 320000
        float4 v = *(const float4*)&x0[(size_t)i * 4];
        ushort4 o;
        o.x = f2b(v.x); o.y = f2b(v.y); o.z = f2b(v.z); o.w = f2b(v.w);
        *(ushort4*)&x0b[(size_t)i * 4] = o;
    } else {
        int i = (bid - PREP_PACK_BLKS - PREP_CVT_BLKS) * 256 + tid;
        if (i < 3 * N_NODES + N_QUEUE) cur_all[i] = 0;
    }
}

// ---------------- aggregation v7: persistent + real-XCC + per-XCD-local queues ----------------
// 2048 persistent blocks (8/CU). Work item = (chunk of 8 nodes) x (64-col group).
// Bucket b <-> (group = b % NG, chunk-range = b / NG); 8 buckets. Each WAVE pops
// its own XCD's bucket first (atomic stays in the local L2 -> fast), then steals
// from the rest guarded by done-flags. Coverage is guaranteed by the 8-step loop
// regardless of what XCC_ID returns; XCC only steers locality.
// Per-XCD steady set: 64-col x-slice (1.28 MB) + srt (<=1.25 MB) << 4 MB L2.
// Per-edge read = 8 lanes x 16 B = one 128 B line; 16 edges in flight per wave.

template <int F, bool MEAN>
__global__ __launch_bounds__(256) void agg_v7(const unsigned short* __restrict__ X,
                                              const int* __restrict__ off,
                                              const int* __restrict__ srt,
                                              unsigned short* __restrict__ msg,
                                              int* __restrict__ ctr,
                                              int* __restrict__ done) {
    constexpr int NG = F / 64;                       // 4 (F=256) or 2 (F=128)
    constexpr int NCHUNK = N_NODES / 8;              // 1250
    constexpr int RANGES = 8 / NG;
    constexpr int CPR = (NCHUNK + RANGES - 1) / RANGES;
    __shared__ int sdone[8];
    if (threadIdx.x < 8) sdone[threadIdx.x] = 0;
    __syncthreads();
    const int lane = threadIdx.x & 63;
    const int h = lane >> 3, c = lane & 7;
    const int xcc = get_xcc_id();

    for (int step = 0; step < 8; ++step) {
        const int b = (xcc + step) & 7;
        const int grp = b % NG;
        const int base = (b / NG) * CPR;
        int limit = NCHUNK - base;
        if (limit > CPR) limit = CPR;
        if (limit < 0) limit = 0;
        const unsigned short* colbase = X + grp * 64 + c * 8;
        for (;;) {
            if (sdone[b] || done[b * 32]) { sdone[b] = 1; break; }
            int idx = 0;
            if (lane == 0) idx = atomicAdd(&ctr[b * 32], 1);
            idx = __shfl(idx, 0, 64);
            if (idx >= limit) {
                if (lane == 0) done[b * 32] = 1;
                sdone[b] = 1;
                break;
            }
            const int chunk = base + idx;
            #pragma unroll 1
            for (int node = chunk * 8; node < chunk * 8 + 8; ++node) {
                const int s0 = off[node], s1 = off[node + 1];
                float acc[8];
                #pragma unroll
                for (int j = 0; j < 8; ++j) acc[j] = 0.f;

                auto addrow = [&](uint4v v) {
                    acc[0] += b2f(v.x & 0xffffu); acc[1] += b2f(v.x >> 16);
                    acc[2] += b2f(v.y & 0xffffu); acc[3] += b2f(v.y >> 16);
                    acc[4] += b2f(v.z & 0xffffu); acc[5] += b2f(v.z >> 16);
                    acc[6] += b2f(v.w & 0xffffu); acc[7] += b2f(v.w >> 16);
                };

                int e = s0;
                for (; e + 15 < s1; e += 16) {
                    int i0 = srt[e + h];
                    int i1 = srt[e + 8 + h];
                    uint4v v0 = *(const uint4v*)(colbase + (size_t)i0 * F);
                    uint4v v1 = *(const uint4v*)(colbase + (size_t)i1 * F);
                    addrow(v0); addrow(v1);
                }
                for (; e + 7 < s1; e += 8) {
                    int i0 = srt[e + h];
                    addrow(*(const uint4v*)(colbase + (size_t)i0 * F));
                }
                if (h < s1 - e) {
                    int i0 = srt[e + h];
                    addrow(*(const uint4v*)(colbase + (size_t)i0 * F));
                }

                #pragma unroll
                for (int j = 0; j < 8; ++j) {
                    acc[j] += __shfl_xor(acc[j], 8);
                    acc[j] += __shfl_xor(acc[j], 16);
                    acc[j] += __shfl_xor(acc[j], 32);
                }

                if (h == 0) {
                    if (MEAN) {
                        float inv = 1.f / fmaxf((float)(s1 - s0), 1.f);
                        #pragma unroll
                        for (int j = 0; j < 8; ++j) acc[j] *= inv;
                    }
                    uint4v o;
                    o.x = (unsigned int)f2b(acc[0]) | ((unsigned int)f2b(acc[1]) << 16);
                    o.y = (unsigned int)f2b(acc[2]) | ((unsigned int)f2b(acc[3]) << 16);
                    o.z = (unsigned int)f2b(acc[4]) | ((unsigned int)f2b(acc[5]) << 16);
                    o.w = (unsigned int)f2b(acc[6]) | ((unsigned int)f2b(acc[7]) << 16);
                    __builtin_nontemporal_store(o, (uint4v*)(msg + (size_t)node * F + grp * 64 + c * 8));
                }
            }
        }
    }
}

// ---------------- MFMA GEMM: 32x128 block tile, 4 waves (16x64 each) ----------------

#define GLOAD_LDS16(g, l) __builtin_amdgcn_global_load_lds( \
    (const __attribute__((address_space(1))) unsigned int*)(g), \
    (__attribute__((address_space(3))) unsigned int*)(l), 16, 0, 0)

template <int K, bool DUAL, bool RELU, bool OUT32>
__global__ __launch_bounds__(256) void gemm_mfma(const unsigned short* __restrict__ A1,
                                                 const unsigned short* __restrict__ Wp1,
                                                 const unsigned short* __restrict__ A2,
                                                 const unsigned short* __restrict__ Wp2,
                                                 const float* __restrict__ bias,
                                                 unsigned short* __restrict__ outb,
                                                 float* __restrict__ outf, int M) {
    constexpr int KB = K / 32;
    constexpr int NT = DUAL ? 2 * KB : KB;
    __shared__ unsigned short As[2][32 * 32];
    __shared__ unsigned short Bs[2][128 * 32];
    const int tid = threadIdx.x;
    const int lane = tid & 63;
    const int w = tid >> 6;
    const int wr = w >> 1, wc = w & 1;
    const int row0 = blockIdx.x * 32;
    const int colblk = blockIdx.y;

    f32x4 acc[4] = {};

    auto stage = [&](int buf, int t) {
        int pass = DUAL ? (t / KB) : 0;
        int kb = DUAL ? (t % KB) : t;
        const unsigned short* A = pass ? A2 : A1;
        const unsigned short* Wp = pass ? Wp2 : Wp1;
        if (w < 2) {
            int row_l = tid >> 2, gp = tid & 3;
            int gs = gp ^ ((row_l >> 1) & 3);
            int row_g = row0 + row_l;
            if (row_g > M - 1) row_g = M - 1;
            const unsigned short* src = A + (size_t)row_g * K + kb * 32 + gs * 8;
            GLOAD_LDS16(src, &As[buf][w * 512]);
        }
        {
            const unsigned short* base = Wp + (size_t)kb * 8192 + (size_t)colblk * 4096;
            GLOAD_LDS16(base + tid * 8,        &Bs[buf][w * 512]);
            GLOAD_LDS16(base + 2048 + tid * 8, &Bs[buf][2048 + w * 512]);
        }
    };

    auto compute = [&](int buf) {
        short8v a, b[4];
        const int g = lane >> 4;
        {
            int row_l = wr * 16 + (lane & 15);
            int q = g ^ ((row_l >> 1) & 3);
            a = *(const short8v*)&As[buf][row_l * 32 + q * 8];
        }
        #pragma unroll
        for (int cf = 0; cf < 4; ++cf) {
            int col_l = wc * 64 + cf * 16 + (lane & 15);
            int q = g ^ ((col_l >> 1) & 3);
            b[cf] = *(const short8v*)&Bs[buf][col_l * 32 + q * 8];
        }
        #pragma unroll
        for (int cf = 0; cf < 4; ++cf)
            acc[cf] = __builtin_amdgcn_mfma_f32_16x16x32_bf16(a, b[cf], acc[cf], 0, 0, 0);
    };

    stage(0, 0);
    __syncthreads();
    int buf = 0;
    for (int t = 0; t < NT; ++t) {
        if (t + 1 < NT) stage(buf ^ 1, t + 1);
        compute(buf);
        __syncthreads();
        buf ^= 1;
    }

    #pragma unroll
    for (int cf = 0; cf < 4; ++cf) {
        int c = colblk * 128 + wc * 64 + cf * 16 + (lane & 15);
        float bv = bias[c];
        #pragma unroll
        for (int i = 0; i < 4; ++i) {
            int r = row0 + wr * 16 + (lane >> 4) * 4 + i;
            if (r < M) {
                float v = acc[cf][i] + bv;
                if (RELU) v = fmaxf(v, 0.f);
                if (OUT32) outf[(size_t)r * HID + c] = v;
                else       outb[(size_t)r * HID + c] = f2b(v);
            }
        }
    }
}

// ---------------- fused final linears: out = (A@W0+b0)@W1+b1, one kernel ----------------

__global__ __launch_bounds__(256) void lin2_fused(const unsigned short* __restrict__ A,
                                                  const unsigned short* __restrict__ Wp0,
                                                  const unsigned short* __restrict__ Wp1,
                                                  const float* __restrict__ bias0,
                                                  const float* __restrict__ bias1,
                                                  float* __restrict__ outf, int M) {
    __shared__ unsigned short As[2][32 * 32];     // 4 KB
    __shared__ unsigned short Bs[2][256 * 32];    // 32 KB
    __shared__ unsigned short T1[32][272];        // 17 KB
    const int tid = threadIdx.x;
    const int lane = tid & 63;
    const int w = tid >> 6;
    const int wr = w >> 1, wc = w & 1;
    const int row0 = blockIdx.x * 32;
    const int g = lane >> 4;
    const int rl = lane & 15;

    auto stageB = [&](int buf, const unsigned short* Wp, int kb) {
        const unsigned short* base = Wp + (size_t)kb * 8192;
        #pragma unroll
        for (int j = 0; j < 4; ++j)
            GLOAD_LDS16(base + j * 2048 + tid * 8, &Bs[buf][j * 2048 + w * 512]);
    };
    auto stageA = [&](int buf, int kb) {
        if (w < 2) {
            int row_l = tid >> 2, gp = tid & 3;
            int gs = gp ^ ((row_l >> 1) & 3);
            int row_g = row0 + row_l;
            if (row_g > M - 1) row_g = M - 1;
            GLOAD_LDS16(A + (size_t)row_g * HID + kb * 32 + gs * 8, &As[buf][w * 512]);
        }
    };

    // ---- Phase A ----
    f32x4 acc[8] = {};
    stageA(0, 0); stageB(0, Wp0, 0);
    __syncthreads();
    int buf = 0;
    for (int t = 0; t < 8; ++t) {
        if (t < 7) { stageA(buf ^ 1, t + 1); stageB(buf ^ 1, Wp0, t + 1); }
        else       { stageB(buf ^ 1, Wp1, 0); }
        int row_l = wr * 16 + rl;
        int qa = g ^ ((row_l >> 1) & 3);
        short8v a = *(const short8v*)&As[buf][row_l * 32 + qa * 8];
        #pragma unroll
        for (int cf = 0; cf < 8; ++cf) {
            int col_l = wc * 128 + cf * 16 + rl;
            int qb = g ^ ((col_l >> 1) & 3);
            short8v b = *(const short8v*)&Bs[buf][col_l * 32 + qb * 8];
            acc[cf] = __builtin_amdgcn_mfma_f32_16x16x32_bf16(a, b, acc[cf], 0, 0, 0);
        }
        __syncthreads();
        buf ^= 1;
    }

    #pragma unroll
    for (int cf = 0; cf < 8; ++cf) {
        int col = wc * 128 + cf * 16 + rl;
        float bv = bias0[col];
        #pragma unroll
        for (int i = 0; i < 4; ++i) {
            int row = wr * 16 + g * 4 + i;
            T1[row][col] = f2b(acc[cf][i] + bv);
        }
    }
    __syncthreads();

    // ---- Phase B ----
    f32x4 acc2[8] = {};
    for (int t = 0; t < 8; ++t) {
        if (t < 7) stageB(buf ^ 1, Wp1, t + 1);
        int row_l = wr * 16 + rl;
        short8v a = *(const short8v*)&T1[row_l][t * 32 + g * 8];
        #pragma unroll
        for (int cf = 0; cf < 8; ++cf) {
            int col_l = wc * 128 + cf * 16 + rl;
            int qb = g ^ ((col_l >> 1) & 3);
            short8v b = *(const short8v*)&Bs[buf][col_l * 32 + qb * 8];
            acc2[cf] = __builtin_amdgcn_mfma_f32_16x16x32_bf16(a, b, acc2[cf], 0, 0, 0);
        }
        __syncthreads();
        buf ^= 1;
    }

    #pragma unroll
    for (int cf = 0; cf < 8; ++cf) {
        int col = wc * 128 + cf * 16 + rl;
        float bv = bias1[col];
        #pragma unroll
        for (int i = 0; i < 4; ++i) {
            int r = row0 + wr * 16 + g * 4 + i;
            if (r < M) outf[(size_t)r * HID + col] = acc2[cf][i] + bv;
        }
    }
}

// ---------------- launch ----------------

static inline char* align256(char* p) {
    return (char*)(((uintptr_t)p + 255) & ~(uintptr_t)255);
}

extern "C" void kernel_launch(void* const* d_in, const int* in_sizes, int n_in,
                              void* d_out, int out_size, void* d_ws, size_t ws_size,
                              hipStream_t stream) {
    const float* x0     = (const float*)d_in[0];
    const int*   ei_con = (const int*)d_in[1];
    const int*   ei_dst = (const int*)d_in[2];
    const int*   ei_trn = (const int*)d_in[3];
    const float* Wmat[12] = {
        (const float*)d_in[5],  (const float*)d_in[4],
        (const float*)d_in[8],  (const float*)d_in[7],
        (const float*)d_in[11], (const float*)d_in[10],
        (const float*)d_in[14], (const float*)d_in[13],
        (const float*)d_in[17], (const float*)d_in[16],
        (const float*)d_in[19],
        (const float*)d_in[19] + HID * HID
    };
    const float* b1 = (const float*)d_in[6];
    const float* b2 = (const float*)d_in[9];
    const float* b3 = (const float*)d_in[12];
    const float* b4 = (const float*)d_in[15];
    const float* b5 = (const float*)d_in[18];
    const float* bL = (const float*)d_in[20];

    const int eCon = in_sizes[1] / 2;
    const int eDst = in_sizes[2] / 2;
    const int eTrn = in_sizes[3] / 2;

    char* p = (char*)d_ws;
    int* cur_all = (int*)p; p = align256(p + (3 * N_NODES + N_QUEUE) * 4);
    int* ctrs    = cur_all + 3 * N_NODES;            // 7 x 256 ints (8 buckets x 32 stride)
    int* dones   = ctrs + 7 * 256;                   // 7 x 256 ints
    int* off_con = (int*)p; p = align256(p + (N_NODES + 1) * 4);
    int* off_dst = (int*)p; p = align256(p + (N_NODES + 1) * 4);
    int* off_trn = (int*)p; p = align256(p + (N_NODES + 1) * 4);
    int* srt_con = (int*)p; p = align256(p + E_CON * 4);
    int* srt_dst = (int*)p; p = align256(p + E_DST * 4);
    int* srt_trn = (int*)p; p = align256(p + E_TRN * 4);
    unsigned short* x0b  = (unsigned short*)p; p = align256(p + (size_t)N_NODES * IN_F * 2);
    unsigned short* msgb = (unsigned short*)p; p = align256(p + (size_t)N_NODES * HID * 2);
    unsigned short* xab  = (unsigned short*)p; p = align256(p + (size_t)N_NODES * HID * 2);
    unsigned short* xbb  = (unsigned short*)p; p = align256(p + (size_t)N_NODES * HID * 2);
    unsigned short* WpBuf[12];
    PackArgs pa;
    for (int m = 0; m < 12; ++m) {
        int K = (m < 2) ? IN_F : HID;
        WpBuf[m] = (unsigned short*)p; p = align256(p + (size_t)K * HID * 2);
        pa.W[m] = Wmat[m];
        pa.O[m] = WpBuf[m];
        pa.K[m] = K;
    }
    float* outp = (float*)d_out;

    CsrArgs ca;
    ca.g[0] = { ei_con, ei_con + eCon, eCon, cur_all,              off_con, srt_con };
    ca.g[1] = { ei_dst, ei_dst + eDst, eDst, cur_all + N_NODES,    off_dst, srt_dst };
    ca.g[2] = { ei_trn, ei_trn + eTrn, eTrn, cur_all + 2*N_NODES,  off_trn, srt_trn };

    // ---- fused prep: pack + cvt + zero (cursors + queue ctr/done) ----
    prep_kernel<<<PREP_PACK_BLKS + PREP_CVT_BLKS + PREP_ZERO_BLKS, 256, 0, stream>>>(pa, x0, x0b, cur_all);

    // ---- CSR build ----
    dim3 hgrid((eCon + 255) / 256, 3);
    hist3<<<hgrid, 256, 0, stream>>>(ca);
    scan3<<<3, 1024, 0, stream>>>(ca);
    fill3<<<hgrid, 256, 0, stream>>>(ca);

    dim3 ggrid((N_NODES + 31) / 32, 2);
    const int PG = 2048;   // persistent agg grid: 8 blocks/CU

    // conv1: relu(msg@Wrel1 + x0@Wroot1 + b1), connections, K=128
    agg_v7<IN_F, false><<<PG, 256, 0, stream>>>(x0b, off_con, srt_con, msgb, ctrs + 0 * 256, dones + 0 * 256);
    gemm_mfma<IN_F, true, true, false><<<ggrid, 256, 0, stream>>>(msgb, WpBuf[0], x0b, WpBuf[1], b1, xab, nullptr, N_NODES);

    // conv2: (no relu), trains
    agg_v7<HID, false><<<PG, 256, 0, stream>>>(xab, off_trn, srt_trn, msgb, ctrs + 1 * 256, dones + 1 * 256);
    gemm_mfma<HID, true, false, false><<<ggrid, 256, 0, stream>>>(msgb, WpBuf[2], xab, WpBuf[3], b2, xbb, nullptr, N_NODES);

    // conv3 x2: relu, mean, connections
    agg_v7<HID, true><<<PG, 256, 0, stream>>>(xbb, off_con, srt_con, msgb, ctrs + 2 * 256, dones + 2 * 256);
    gemm_mfma<HID, true, true, false><<<ggrid, 256, 0, stream>>>(msgb, WpBuf[4], xbb, WpBuf[5], b3, xab, nullptr, N_NODES);
    agg_v7<HID, true><<<PG, 256, 0, stream>>>(xab, off_con, srt_con, msgb, ctrs + 3 * 256, dones + 3 * 256);
    gemm_mfma<HID, true, true, false><<<ggrid, 256, 0, stream>>>(msgb, WpBuf[4], xab, WpBuf[5], b3, xbb, nullptr, N_NODES);

    // conv4: relu, add, destinations
    agg_v7<HID, false><<<PG, 256, 0, stream>>>(xbb, off_dst, srt_dst, msgb, ctrs + 4 * 256, dones + 4 * 256);
    gemm_mfma<HID, true, true, false><<<ggrid, 256, 0, stream>>>(msgb, WpBuf[6], xbb, WpBuf[7], b4, xab, nullptr, N_NODES);

    // conv5 x2: relu, add, connections
    agg_v7<HID, false><<<PG, 256, 0, stream>>>(xab, off_con, srt_con, msgb, ctrs + 5 * 256, dones + 5 * 256);
    gemm_mfma<HID, true, true, false><<<ggrid, 256, 0, stream>>>(msgb, WpBuf[8], xab, WpBuf[9], b5, xbb, nullptr, N_NODES);
    agg_v7<HID, false><<<PG, 256, 0, stream>>>(xbb, off_con, srt_con, msgb, ctrs + 6 * 256, dones + 6 * 256);
    gemm_mfma<HID, true, true, false><<<ggrid, 256, 0, stream>>>(msgb, WpBuf[8], xbb, WpBuf[9], b5, xab, nullptr, N_NODES);

    // fused final linears
    lin2_fused<<<(N_NODES + 31) / 32, 256, 0, stream>>>(xab, WpBuf[10], WpBuf[11], bL, bL + HID, outp, N_NODES);
}

// Round 12
// 269.241 us; speedup vs baseline: 2.3789x; 2.3789x over previous
//
#include <hip/hip_runtime.h>
#include <hip/hip_bf16.h>

#define N_NODES 10000
#define HID 256
#define IN_F 128
#define E_CON 320000
#define E_DST 100000
#define E_TRN 50000

typedef __attribute__((ext_vector_type(8))) short short8v;
typedef __attribute__((ext_vector_type(4))) float f32x4;
typedef unsigned int uint4v __attribute__((ext_vector_type(4)));

__device__ __forceinline__ float b2f(unsigned int u) {
    return __uint_as_float(u << 16);
}
__device__ __forceinline__ unsigned short f2b(float f) {
    unsigned int u = __float_as_uint(f);
    unsigned int r = (u + 0x7fffu + ((u >> 16) & 1u)) >> 16;
    return (unsigned short)r;
}

// ---------------- CSR build (fused, 3 graphs) ----------------

struct GraphDesc {
    const int* src;
    const int* dst;
    int nE;
    int* cur;
    int* off;
    int* srt;
};
struct CsrArgs { GraphDesc g[3]; };

__global__ void hist3(CsrArgs a) {
    const GraphDesc& gg = a.g[blockIdx.y];
    int i = blockIdx.x * blockDim.x + threadIdx.x;
    if (i < gg.nE) atomicAdd(&gg.cur[gg.dst[i]], 1);
}

__global__ void fill3(CsrArgs a) {
    const GraphDesc& gg = a.g[blockIdx.y];
    int i = blockIdx.x * blockDim.x + threadIdx.x;
    if (i < gg.nE) {
        int p = atomicAdd(&gg.cur[gg.dst[i]], 1);
        gg.srt[p] = gg.src[i];
    }
}

// One block per graph, 1024 threads, shfl-based exclusive scan over N_NODES.
__global__ __launch_bounds__(1024) void scan3(CsrArgs a) {
    const GraphDesc& gg = a.g[blockIdx.x];
    int* cur = gg.cur;
    int* off = gg.off;
    const int n = N_NODES;
    __shared__ int wsum[16];
    __shared__ int wtot;
    __shared__ int carry_sh;
    int tid = threadIdx.x;
    int lane = tid & 63;
    int w = tid >> 6;
    if (tid == 0) carry_sh = 0;
    __syncthreads();
    for (int base = 0; base < n; base += 1024) {
        int i = base + tid;
        int v = (i < n) ? cur[i] : 0;
        int s = v;
        #pragma unroll
        for (int d = 1; d < 64; d <<= 1) {
            int t = __shfl_up(s, d, 64);
            if (lane >= d) s += t;
        }
        if (lane == 63) wsum[w] = s;
        __syncthreads();
        if (w == 0 && lane < 16) {
            int t = wsum[lane];
            int ss = t;
            #pragma unroll
            for (int d = 1; d < 16; d <<= 1) {
                int u = __shfl_up(ss, d, 64);
                if (lane >= d) ss += u;
            }
            wsum[lane] = ss - t;
            if (lane == 15) wtot = ss;
        }
        __syncthreads();
        int carry = carry_sh;
        int excl = s - v + wsum[w] + carry;
        if (i < n) { off[i] = excl; cur[i] = excl; }
        __syncthreads();
        if (tid == 0) carry_sh += wtot;
        __syncthreads();
    }
    if (threadIdx.x == 0) off[n] = carry_sh;
}

// ---------------- fused prep: weight pack + x0 cvt + cursor zero ----------------

struct PackArgs {
    const float* W[12];
    unsigned short* O[12];
    int K[12];
};

#define PREP_PACK_BLKS 384      /* 12 matrices x 32 blocks */
#define PREP_CVT_BLKS  1250     /* 320000 float4 / 256 */
#define PREP_ZERO_BLKS 118      /* 30000 ints / 256 */

__global__ void prep_kernel(PackArgs pa, const float* __restrict__ x0,
                            unsigned short* __restrict__ x0b, int* __restrict__ cur_all) {
    int bid = blockIdx.x;
    int tid = threadIdx.x;
    if (bid < PREP_PACK_BLKS) {
        int m = bid >> 5;
        int K = pa.K[m];
        int granules = (K / 32) * 1024;
        int p = (bid & 31) * 256 + tid;
        if (p >= granules) return;
        int kb = p >> 10;
        int r  = p & 1023;
        int c  = r >> 2;
        int gp = r & 3;
        int g  = gp ^ ((c >> 1) & 3);
        const float* W = pa.W[m];
        unsigned short* O = pa.O[m] + (size_t)p * 8;
        int krow = kb * 32 + g * 8;
        ushort4 lo, hi;
        lo.x = f2b(W[(size_t)(krow + 0) * HID + c]);
        lo.y = f2b(W[(size_t)(krow + 1) * HID + c]);
        lo.z = f2b(W[(size_t)(krow + 2) * HID + c]);
        lo.w = f2b(W[(size_t)(krow + 3) * HID + c]);
        hi.x = f2b(W[(size_t)(krow + 4) * HID + c]);
        hi.y = f2b(W[(size_t)(krow + 5) * HID + c]);
        hi.z = f2b(W[(size_t)(krow + 6) * HID + c]);
        hi.w = f2b(W[(size_t)(krow + 7) * HID + c]);
        *(ushort4*)&O[0] = lo;
        *(ushort4*)&O[4] = hi;
    } else if (bid < PREP_PACK_BLKS + PREP_CVT_BLKS) {
        int i = (bid - PREP_PACK_BLKS) * 256 + tid;   // < 320000
        float4 v = *(const float4*)&x0[(size_t)i * 4];
        ushort4 o;
        o.x = f2b(v.x); o.y = f2b(v.y); o.z = f2b(v.z); o.w = f2b(v.w);
        *(ushort4*)&x0b[(size_t)i * 4] = o;
    } else {
        int i = (bid - PREP_PACK_BLKS - PREP_CVT_BLKS) * 256 + tid;
        if (i < 3 * N_NODES) cur_all[i] = 0;
    }
}

// ---------------- aggregation v4 (best measured): XCD-parity column halves ----------------

template <int F, bool MEAN>
__global__ __launch_bounds__(256) void agg_bf16(const unsigned short* __restrict__ xb,
                                                const int* __restrict__ off,
                                                const int* __restrict__ srt,
                                                unsigned short* __restrict__ msg) {
    constexpr int HALVES = F / 128;
    int bid = blockIdx.x;
    int half = (HALVES == 2) ? (bid & 1) : 0;
    int nodeblk = (HALVES == 2) ? (bid >> 1) : bid;
    int wv = threadIdx.x >> 6;
    int lane = threadIdx.x & 63;
    int h = lane >> 4, c = lane & 15;
    int node = nodeblk * 4 + wv;
    int col0 = half * 128 + c * 8;
    int s0 = off[node], s1 = off[node + 1];
    float acc[8];
    #pragma unroll
    for (int j = 0; j < 8; ++j) acc[j] = 0.f;
    const unsigned short* colbase = xb + col0;

    auto addrow = [&](uint4v v) {
        acc[0] += b2f(v.x & 0xffffu); acc[1] += b2f(v.x >> 16);
        acc[2] += b2f(v.y & 0xffffu); acc[3] += b2f(v.y >> 16);
        acc[4] += b2f(v.z & 0xffffu); acc[5] += b2f(v.z >> 16);
        acc[6] += b2f(v.w & 0xffffu); acc[7] += b2f(v.w >> 16);
    };

    int e = s0;
    for (; e + 15 < s1; e += 16) {
        int i0 = srt[e + h];
        int i1 = srt[e + 4 + h];
        int i2 = srt[e + 8 + h];
        int i3 = srt[e + 12 + h];
        uint4v v0 = *(const uint4v*)(colbase + (size_t)i0 * F);
        uint4v v1 = *(const uint4v*)(colbase + (size_t)i1 * F);
        uint4v v2 = *(const uint4v*)(colbase + (size_t)i2 * F);
        uint4v v3 = *(const uint4v*)(colbase + (size_t)i3 * F);
        addrow(v0); addrow(v1); addrow(v2); addrow(v3);
    }
    for (; e + 3 < s1; e += 4) {
        int i0 = srt[e + h];
        addrow(*(const uint4v*)(colbase + (size_t)i0 * F));
    }
    int rem = s1 - e;
    if (h < rem) {
        int i0 = srt[e + h];
        addrow(*(const uint4v*)(colbase + (size_t)i0 * F));
    }

    #pragma unroll
    for (int j = 0; j < 8; ++j) {
        acc[j] += __shfl_xor(acc[j], 16);
        acc[j] += __shfl_xor(acc[j], 32);
    }

    if (h == 0) {
        if (MEAN) {
            float inv = 1.f / fmaxf((float)(s1 - s0), 1.f);
            #pragma unroll
            for (int j = 0; j < 8; ++j) acc[j] *= inv;
        }
        uint4v o;
        o.x = (unsigned int)f2b(acc[0]) | ((unsigned int)f2b(acc[1]) << 16);
        o.y = (unsigned int)f2b(acc[2]) | ((unsigned int)f2b(acc[3]) << 16);
        o.z = (unsigned int)f2b(acc[4]) | ((unsigned int)f2b(acc[5]) << 16);
        o.w = (unsigned int)f2b(acc[6]) | ((unsigned int)f2b(acc[7]) << 16);
        __builtin_nontemporal_store(o, (uint4v*)(msg + (size_t)node * F + col0));
    }
}

// ---------------- MFMA GEMM: 32x128 block tile, 4 waves (16x64 each) ----------------

#define GLOAD_LDS16(g, l) __builtin_amdgcn_global_load_lds( \
    (const __attribute__((address_space(1))) unsigned int*)(g), \
    (__attribute__((address_space(3))) unsigned int*)(l), 16, 0, 0)

template <int K, bool DUAL, bool RELU, bool OUT32>
__global__ __launch_bounds__(256) void gemm_mfma(const unsigned short* __restrict__ A1,
                                                 const unsigned short* __restrict__ Wp1,
                                                 const unsigned short* __restrict__ A2,
                                                 const unsigned short* __restrict__ Wp2,
                                                 const float* __restrict__ bias,
                                                 unsigned short* __restrict__ outb,
                                                 float* __restrict__ outf, int M) {
    constexpr int KB = K / 32;
    constexpr int NT = DUAL ? 2 * KB : KB;
    __shared__ unsigned short As[2][32 * 32];
    __shared__ unsigned short Bs[2][128 * 32];
    const int tid = threadIdx.x;
    const int lane = tid & 63;
    const int w = tid >> 6;
    const int wr = w >> 1, wc = w & 1;
    const int row0 = blockIdx.x * 32;
    const int colblk = blockIdx.y;

    f32x4 acc[4] = {};

    auto stage = [&](int buf, int t) {
        int pass = DUAL ? (t / KB) : 0;
        int kb = DUAL ? (t % KB) : t;
        const unsigned short* A = pass ? A2 : A1;
        const unsigned short* Wp = pass ? Wp2 : Wp1;
        if (w < 2) {
            int row_l = tid >> 2, gp = tid & 3;
            int gs = gp ^ ((row_l >> 1) & 3);
            int row_g = row0 + row_l;
            if (row_g > M - 1) row_g = M - 1;
            const unsigned short* src = A + (size_t)row_g * K + kb * 32 + gs * 8;
            GLOAD_LDS16(src, &As[buf][w * 512]);
        }
        {
            const unsigned short* base = Wp + (size_t)kb * 8192 + (size_t)colblk * 4096;
            GLOAD_LDS16(base + tid * 8,        &Bs[buf][w * 512]);
            GLOAD_LDS16(base + 2048 + tid * 8, &Bs[buf][2048 + w * 512]);
        }
    };

    auto compute = [&](int buf) {
        short8v a, b[4];
        const int g = lane >> 4;
        {
            int row_l = wr * 16 + (lane & 15);
            int q = g ^ ((row_l >> 1) & 3);
            a = *(const short8v*)&As[buf][row_l * 32 + q * 8];
        }
        #pragma unroll
        for (int cf = 0; cf < 4; ++cf) {
            int col_l = wc * 64 + cf * 16 + (lane & 15);
            int q = g ^ ((col_l >> 1) & 3);
            b[cf] = *(const short8v*)&Bs[buf][col_l * 32 + q * 8];
        }
        #pragma unroll
        for (int cf = 0; cf < 4; ++cf)
            acc[cf] = __builtin_amdgcn_mfma_f32_16x16x32_bf16(a, b[cf], acc[cf], 0, 0, 0);
    };

    stage(0, 0);
    __syncthreads();
    int buf = 0;
    for (int t = 0; t < NT; ++t) {
        if (t + 1 < NT) stage(buf ^ 1, t + 1);
        compute(buf);
        __syncthreads();
        buf ^= 1;
    }

    #pragma unroll
    for (int cf = 0; cf < 4; ++cf) {
        int c = colblk * 128 + wc * 64 + cf * 16 + (lane & 15);
        float bv = bias[c];
        #pragma unroll
        for (int i = 0; i < 4; ++i) {
            int r = row0 + wr * 16 + (lane >> 4) * 4 + i;
            if (r < M) {
                float v = acc[cf][i] + bv;
                if (RELU) v = fmaxf(v, 0.f);
                if (OUT32) outf[(size_t)r * HID + c] = v;
                else       outb[(size_t)r * HID + c] = f2b(v);
            }
        }
    }
}

// ---------------- fused final linears: out = (A@W0+b0)@W1+b1, one kernel ----------------

__global__ __launch_bounds__(256) void lin2_fused(const unsigned short* __restrict__ A,
                                                  const unsigned short* __restrict__ Wp0,
                                                  const unsigned short* __restrict__ Wp1,
                                                  const float* __restrict__ bias0,
                                                  const float* __restrict__ bias1,
                                                  float* __restrict__ outf, int M) {
    __shared__ unsigned short As[2][32 * 32];     // 4 KB
    __shared__ unsigned short Bs[2][256 * 32];    // 32 KB
    __shared__ unsigned short T1[32][272];        // 17 KB
    const int tid = threadIdx.x;
    const int lane = tid & 63;
    const int w = tid >> 6;
    const int wr = w >> 1, wc = w & 1;
    const int row0 = blockIdx.x * 32;
    const int g = lane >> 4;
    const int rl = lane & 15;

    auto stageB = [&](int buf, const unsigned short* Wp, int kb) {
        const unsigned short* base = Wp + (size_t)kb * 8192;
        #pragma unroll
        for (int j = 0; j < 4; ++j)
            GLOAD_LDS16(base + j * 2048 + tid * 8, &Bs[buf][j * 2048 + w * 512]);
    };
    auto stageA = [&](int buf, int kb) {
        if (w < 2) {
            int row_l = tid >> 2, gp = tid & 3;
            int gs = gp ^ ((row_l >> 1) & 3);
            int row_g = row0 + row_l;
            if (row_g > M - 1) row_g = M - 1;
            GLOAD_LDS16(A + (size_t)row_g * HID + kb * 32 + gs * 8, &As[buf][w * 512]);
        }
    };

    // ---- Phase A ----
    f32x4 acc[8] = {};
    stageA(0, 0); stageB(0, Wp0, 0);
    __syncthreads();
    int buf = 0;
    for (int t = 0; t < 8; ++t) {
        if (t < 7) { stageA(buf ^ 1, t + 1); stageB(buf ^ 1, Wp0, t + 1); }
        else       { stageB(buf ^ 1, Wp1, 0); }
        int row_l = wr * 16 + rl;
        int qa = g ^ ((row_l >> 1) & 3);
        short8v a = *(const short8v*)&As[buf][row_l * 32 + qa * 8];
        #pragma unroll
        for (int cf = 0; cf < 8; ++cf) {
            int col_l = wc * 128 + cf * 16 + rl;
            int qb = g ^ ((col_l >> 1) & 3);
            short8v b = *(const short8v*)&Bs[buf][col_l * 32 + qb * 8];
            acc[cf] = __builtin_amdgcn_mfma_f32_16x16x32_bf16(a, b, acc[cf], 0, 0, 0);
        }
        __syncthreads();
        buf ^= 1;
    }

    #pragma unroll
    for (int cf = 0; cf < 8; ++cf) {
        int col = wc * 128 + cf * 16 + rl;
        float bv = bias0[col];
        #pragma unroll
        for (int i = 0; i < 4; ++i) {
            int row = wr * 16 + g * 4 + i;
            T1[row][col] = f2b(acc[cf][i] + bv);
        }
    }
    __syncthreads();

    // ---- Phase B ----
    f32x4 acc2[8] = {};
    for (int t = 0; t < 8; ++t) {
        if (t < 7) stageB(buf ^ 1, Wp1, t + 1);
        int row_l = wr * 16 + rl;
        short8v a = *(const short8v*)&T1[row_l][t * 32 + g * 8];
        #pragma unroll
        for (int cf = 0; cf < 8; ++cf) {
            int col_l = wc * 128 + cf * 16 + rl;
            int qb = g ^ ((col_l >> 1) & 3);
            short8v b = *(const short8v*)&Bs[buf][col_l * 32 + qb * 8];
            acc2[cf] = __builtin_amdgcn_mfma_f32_16x16x32_bf16(a, b, acc2[cf], 0, 0, 0);
        }
        __syncthreads();
        buf ^= 1;
    }

    #pragma unroll
    for (int cf = 0; cf < 8; ++cf) {
        int col = wc * 128 + cf * 16 + rl;
        float bv = bias1[col];
        #pragma unroll
        for (int i = 0; i < 4; ++i) {
            int r = row0 + wr * 16 + g * 4 + i;
            if (r < M) outf[(size_t)r * HID + col] = acc2[cf][i] + bv;
        }
    }
}

// ---------------- launch ----------------

static inline char* align256(char* p) {
    return (char*)(((uintptr_t)p + 255) & ~(uintptr_t)255);
}

extern "C" void kernel_launch(void* const* d_in, const int* in_sizes, int n_in,
                              void* d_out, int out_size, void* d_ws, size_t ws_size,
                              hipStream_t stream) {
    const float* x0     = (const float*)d_in[0];
    const int*   ei_con = (const int*)d_in[1];
    const int*   ei_dst = (const int*)d_in[2];
    const int*   ei_trn = (const int*)d_in[3];
    const float* Wmat[12] = {
        (const float*)d_in[5],  (const float*)d_in[4],
        (const float*)d_in[8],  (const float*)d_in[7],
        (const float*)d_in[11], (const float*)d_in[10],
        (const float*)d_in[14], (const float*)d_in[13],
        (const float*)d_in[17], (const float*)d_in[16],
        (const float*)d_in[19],
        (const float*)d_in[19] + HID * HID
    };
    const float* b1 = (const float*)d_in[6];
    const float* b2 = (const float*)d_in[9];
    const float* b3 = (const float*)d_in[12];
    const float* b4 = (const float*)d_in[15];
    const float* b5 = (const float*)d_in[18];
    const float* bL = (const float*)d_in[20];

    const int eCon = in_sizes[1] / 2;
    const int eDst = in_sizes[2] / 2;
    const int eTrn = in_sizes[3] / 2;

    char* p = (char*)d_ws;
    int* cur_all = (int*)p; p = align256(p + 3 * N_NODES * 4);
    int* off_con = (int*)p; p = align256(p + (N_NODES + 1) * 4);
    int* off_dst = (int*)p; p = align256(p + (N_NODES + 1) * 4);
    int* off_trn = (int*)p; p = align256(p + (N_NODES + 1) * 4);
    int* srt_con = (int*)p; p = align256(p + E_CON * 4);
    int* srt_dst = (int*)p; p = align256(p + E_DST * 4);
    int* srt_trn = (int*)p; p = align256(p + E_TRN * 4);
    unsigned short* x0b  = (unsigned short*)p; p = align256(p + (size_t)N_NODES * IN_F * 2);
    unsigned short* msgb = (unsigned short*)p; p = align256(p + (size_t)N_NODES * HID * 2);
    unsigned short* xab  = (unsigned short*)p; p = align256(p + (size_t)N_NODES * HID * 2);
    unsigned short* xbb  = (unsigned short*)p; p = align256(p + (size_t)N_NODES * HID * 2);
    unsigned short* WpBuf[12];
    PackArgs pa;
    for (int m = 0; m < 12; ++m) {
        int K = (m < 2) ? IN_F : HID;
        WpBuf[m] = (unsigned short*)p; p = align256(p + (size_t)K * HID * 2);
        pa.W[m] = Wmat[m];
        pa.O[m] = WpBuf[m];
        pa.K[m] = K;
    }
    float* outp = (float*)d_out;

    CsrArgs ca;
    ca.g[0] = { ei_con, ei_con + eCon, eCon, cur_all,              off_con, srt_con };
    ca.g[1] = { ei_dst, ei_dst + eDst, eDst, cur_all + N_NODES,    off_dst, srt_dst };
    ca.g[2] = { ei_trn, ei_trn + eTrn, eTrn, cur_all + 2*N_NODES,  off_trn, srt_trn };

    // ---- fused prep: pack + cvt + zero ----
    prep_kernel<<<PREP_PACK_BLKS + PREP_CVT_BLKS + PREP_ZERO_BLKS, 256, 0, stream>>>(pa, x0, x0b, cur_all);

    // ---- CSR build ----
    dim3 hgrid((eCon + 255) / 256, 3);
    hist3<<<hgrid, 256, 0, stream>>>(ca);
    scan3<<<3, 1024, 0, stream>>>(ca);
    fill3<<<hgrid, 256, 0, stream>>>(ca);

    dim3 ggrid((N_NODES + 31) / 32, 2);
    const int agrid1 = N_NODES / 4;        // F=128: one column half
    const int agrid2 = (N_NODES / 4) * 2;  // F=256: XCD-parity halves

    // conv1: relu(msg@Wrel1 + x0@Wroot1 + b1), connections, K=128
    agg_bf16<IN_F, false><<<agrid1, 256, 0, stream>>>(x0b, off_con, srt_con, msgb);
    gemm_mfma<IN_F, true, true, false><<<ggrid, 256, 0, stream>>>(msgb, WpBuf[0], x0b, WpBuf[1], b1, xab, nullptr, N_NODES);

    // conv2: (no relu), trains
    agg_bf16<HID, false><<<agrid2, 256, 0, stream>>>(xab, off_trn, srt_trn, msgb);
    gemm_mfma<HID, true, false, false><<<ggrid, 256, 0, stream>>>(msgb, WpBuf[2], xab, WpBuf[3], b2, xbb, nullptr, N_NODES);

    // conv3 x2: relu, mean, connections
    agg_bf16<HID, true><<<agrid2, 256, 0, stream>>>(xbb, off_con, srt_con, msgb);
    gemm_mfma<HID, true, true, false><<<ggrid, 256, 0, stream>>>(msgb, WpBuf[4], xbb, WpBuf[5], b3, xab, nullptr, N_NODES);
    agg_bf16<HID, true><<<agrid2, 256, 0, stream>>>(xab, off_con, srt_con, msgb);
    gemm_mfma<HID, true, true, false><<<ggrid, 256, 0, stream>>>(msgb, WpBuf[4], xab, WpBuf[5], b3, xbb, nullptr, N_NODES);

    // conv4: relu, add, destinations
    agg_bf16<HID, false><<<agrid2, 256, 0, stream>>>(xbb, off_dst, srt_dst, msgb);
    gemm_mfma<HID, true, true, false><<<ggrid, 256, 0, stream>>>(msgb, WpBuf[6], xbb, WpBuf[7], b4, xab, nullptr, N_NODES);

    // conv5 x2: relu, add, connections
    agg_bf16<HID, false><<<agrid2, 256, 0, stream>>>(xab, off_con, srt_con, msgb);
    gemm_mfma<HID, true, true, false><<<ggrid, 256, 0, stream>>>(msgb, WpBuf[8], xab, WpBuf[9], b5, xbb, nullptr, N_NODES);
    agg_bf16<HID, false><<<agrid2, 256, 0, stream>>>(xbb, off_con, srt_con, msgb);
    gemm_mfma<HID, true, true, false><<<ggrid, 256, 0, stream>>>(msgb, WpBuf[8], xbb, WpBuf[9], b5, xab, nullptr, N_NODES);

    // fused final linears
    lin2_fused<<<(N_NODES + 31) / 32, 256, 0, stream>>>(xab, WpBuf[10], WpBuf[11], bL, bL + HID, outp, N_NODES);
}